// Round 6
// baseline (425.733 us; speedup 1.0000x reference)
//
#include <hip/hip_runtime.h>
#include <hip/hip_cooperative_groups.h>

namespace cg = cooperative_groups;

#define B_ 8
#define S_ 1024
#define D_ 2048
#define E_ 2
#define NROWS (E_ * D_ + E_)
#define GRID_ 1024   // 4 blocks/CU x 256 CUs: exact cooperative co-residency

typedef float f32x4 __attribute__((ext_vector_type(4)));

__device__ inline float wave_reduce_sum(float v) {
    #pragma unroll
    for (int off = 32; off > 0; off >>= 1) v += __shfl_down(v, off, 64);
    return v;
}
__device__ inline float wave_reduce_max(float v) {
    #pragma unroll
    for (int off = 32; off > 0; off >>= 1) v = fmaxf(v, __shfl_down(v, off, 64));
    return v;
}

// ==================== fused cooperative kernel ====================
// Phase A: W-row reduce (nt) + wg->LDS + x first-half prefetch into regs + gate partials
// Phase B: Wsum->LDS, dots (1st half from regs, 2nd half streamed), y write
// Phase C: log_softmax on blocks 0..7
__global__ __launch_bounds__(256, 4) void fused_kernel(
        const float* __restrict__ x, const float* __restrict__ wg,
        const float* __restrict__ W, const float* __restrict__ bvec,
        float* __restrict__ Wsum, float* __restrict__ bsum,
        float* __restrict__ y, float* __restrict__ out) {
    __shared__ float lw0[D_], lw1[D_], lg0[D_], lg1[D_];   // 32 KB
    __shared__ float red[4];
    __shared__ float M_s, L_s;
    const int tid = threadIdx.x;
    const int wave = tid >> 6, lane = tid & 63;
    cg::grid_group grid = cg::this_grid();

    // ---------------- Phase A ----------------
    // stage de-interleaved gate columns (wg is [D,2])
    {
        const f32x4* wgg = (const f32x4*)wg;
        f32x4* g0 = (f32x4*)lg0; f32x4* g1 = (f32x4*)lg1;
        for (int i = tid; i < D_ / 4; i += 256) {
            f32x4 u = wgg[2 * i], v = wgg[2 * i + 1];
            f32x4 a, b;
            a.x = u.x; a.y = u.z; a.z = v.x; a.w = v.z;
            b.x = u.y; b.y = u.w; b.z = v.y; b.w = v.w;
            g0[i] = a; g1[i] = b;
        }
    }

    // W row reduction: one row per wave (4096 rows over 1024 blocks)
    {
        const int row = blockIdx.x * 4 + wave;
        const f32x4* s4 = (const f32x4*)(W + (size_t)row * D_);
        float s = 0.0f;
        #pragma unroll
        for (int j = 0; j < 8; ++j) {
            f32x4 v = __builtin_nontemporal_load(&s4[lane + j * 64]);
            s += (v.x + v.y) + (v.z + v.w);
        }
        s = wave_reduce_sum(s);
        if (lane == 0) Wsum[row] = s;
        if (blockIdx.x == 0 && wave < E_) {            // bias rows
            const f32x4* b4 = (const f32x4*)(bvec + (size_t)wave * D_);
            float t = 0.0f;
            #pragma unroll
            for (int j = 0; j < 8; ++j) {
                f32x4 v = b4[lane + j * 64];
                t += (v.x + v.y) + (v.z + v.w);
            }
            t = wave_reduce_sum(t);
            if (lane == 0) bsum[wave] = t;
        }
    }
    __syncthreads();   // lg staged

    // x first-half prefetch (regs) + gate first-half partials
    const int t0 = blockIdx.x * 8 + wave * 2;
    const int t1 = t0 + 1;
    const f32x4* xa = (const f32x4*)(x + (size_t)t0 * D_);
    const f32x4* xb = (const f32x4*)(x + (size_t)t1 * D_);
    const f32x4* g0r = (const f32x4*)lg0;
    const f32x4* g1r = (const f32x4*)lg1;

    f32x4 xr0[4], xr1[4];
    #pragma unroll
    for (int j = 0; j < 4; ++j) {
        const int i = lane + j * 64;
        xr0[j] = __builtin_nontemporal_load(&xa[i]);
        xr1[j] = __builtin_nontemporal_load(&xb[i]);
    }
    float g0a = 0, g1a = 0, g0b = 0, g1b = 0;
    #pragma unroll
    for (int j = 0; j < 4; ++j) {
        const int i = lane + j * 64;
        f32x4 u = g0r[i], v = g1r[i];
        g0a += xr0[j].x * u.x + xr0[j].y * u.y + xr0[j].z * u.z + xr0[j].w * u.w;
        g1a += xr0[j].x * v.x + xr0[j].y * v.y + xr0[j].z * v.z + xr0[j].w * v.w;
        g0b += xr1[j].x * u.x + xr1[j].y * u.y + xr1[j].z * u.z + xr1[j].w * u.w;
        g1b += xr1[j].x * v.x + xr1[j].y * v.y + xr1[j].z * v.z + xr1[j].w * v.w;
    }

    __threadfence();
    grid.sync();

    // ---------------- Phase B ----------------
    {
        const f32x4* w0g = (const f32x4*)(Wsum);
        const f32x4* w1g = (const f32x4*)(Wsum + D_);
        f32x4* l0 = (f32x4*)lw0; f32x4* l1 = (f32x4*)lw1;
        for (int i = tid; i < D_ / 4; i += 256) { l0[i] = w0g[i]; l1[i] = w1g[i]; }
    }
    __syncthreads();

    const f32x4* l0r = (const f32x4*)lw0;
    const f32x4* l1r = (const f32x4*)lw1;
    float d0a = 0, d1a = 0, d0b = 0, d1b = 0;
    #pragma unroll
    for (int j = 0; j < 4; ++j) {            // first half: x from regs
        const int i = lane + j * 64;
        f32x4 a = l0r[i], c = l1r[i];
        d0a += xr0[j].x * a.x + xr0[j].y * a.y + xr0[j].z * a.z + xr0[j].w * a.w;
        d1a += xr0[j].x * c.x + xr0[j].y * c.y + xr0[j].z * c.z + xr0[j].w * c.w;
        d0b += xr1[j].x * a.x + xr1[j].y * a.y + xr1[j].z * a.z + xr1[j].w * a.w;
        d1b += xr1[j].x * c.x + xr1[j].y * c.y + xr1[j].z * c.z + xr1[j].w * c.w;
    }
    #pragma unroll
    for (int j = 4; j < 8; ++j) {            // second half: streamed
        const int i = lane + j * 64;
        f32x4 x0 = __builtin_nontemporal_load(&xa[i]);
        f32x4 x1 = __builtin_nontemporal_load(&xb[i]);
        f32x4 a = l0r[i], c = l1r[i], u = g0r[i], v = g1r[i];
        d0a += x0.x * a.x + x0.y * a.y + x0.z * a.z + x0.w * a.w;
        d1a += x0.x * c.x + x0.y * c.y + x0.z * c.z + x0.w * c.w;
        g0a += x0.x * u.x + x0.y * u.y + x0.z * u.z + x0.w * u.w;
        g1a += x0.x * v.x + x0.y * v.y + x0.z * v.z + x0.w * v.w;
        d0b += x1.x * a.x + x1.y * a.y + x1.z * a.z + x1.w * a.w;
        d1b += x1.x * c.x + x1.y * c.y + x1.z * c.z + x1.w * c.w;
        g0b += x1.x * u.x + x1.y * u.y + x1.z * u.z + x1.w * u.w;
        g1b += x1.x * v.x + x1.y * v.y + x1.z * v.z + x1.w * v.w;
    }
    d0a = wave_reduce_sum(d0a); d1a = wave_reduce_sum(d1a);
    g0a = wave_reduce_sum(g0a); g1a = wave_reduce_sum(g1a);
    d0b = wave_reduce_sum(d0b); d1b = wave_reduce_sum(d1b);
    g0b = wave_reduce_sum(g0b); g1b = wave_reduce_sum(g1b);

    if (lane == 0) {
        {
            const int idx = (g1a > g0a) ? 1 : 0;                 // argmax first-occurrence
            const float diff = idx ? (g0a - g1a) : (g1a - g0a);  // <= 0
            const float gate = 1.0f / (1.0f + expf(diff));
            y[t0] = gate * ((idx ? d1a : d0a) + bsum[idx]);
        }
        {
            const int idx = (g1b > g0b) ? 1 : 0;
            const float diff = idx ? (g0b - g1b) : (g1b - g0b);
            const float gate = 1.0f / (1.0f + expf(diff));
            y[t1] = gate * ((idx ? d1b : d0b) + bsum[idx]);
        }
    }

    __threadfence();
    grid.sync();

    // ---------------- Phase C: log_softmax (blocks 0..7) ----------------
    if (blockIdx.x < B_) {
        const int b = blockIdx.x;
        const f32x4* row4 = (const f32x4*)(y + (size_t)b * S_);
        f32x4 v = row4[tid];
        float m = fmaxf(fmaxf(v.x, v.y), fmaxf(v.z, v.w));
        m = wave_reduce_max(m);
        if (lane == 0) red[wave] = m;
        __syncthreads();
        if (tid == 0) M_s = fmaxf(fmaxf(red[0], red[1]), fmaxf(red[2], red[3]));
        __syncthreads();
        const float M = M_s;
        float s = expf(v.x - M) + expf(v.y - M) + expf(v.z - M) + expf(v.w - M);
        s = wave_reduce_sum(s);
        __syncthreads();
        if (lane == 0) red[wave] = s;
        __syncthreads();
        if (tid == 0) L_s = M + logf(red[0] + red[1] + red[2] + red[3]);
        __syncthreads();
        const float lse = L_s;
        f32x4 o;
        o.x = v.x - lse; o.y = v.y - lse; o.z = v.z - lse; o.w = v.w - lse;
        ((f32x4*)(out + (size_t)b * S_))[tid] = o;
    }
}

// ==================== fallback path (proven 3-kernel, nt loads) ====================
__global__ __launch_bounds__(256) void reduce_rows_kernel(
        const float* __restrict__ W, const float* __restrict__ bvec,
        float* __restrict__ Wsum, float* __restrict__ bsum) {
    const int wave = threadIdx.x >> 6, lane = threadIdx.x & 63;
    const int row = blockIdx.x * 4 + wave;
    if (row >= NROWS) return;
    const float* src = (row < E_ * D_) ? (W + (size_t)row * D_)
                                       : (bvec + (size_t)(row - E_ * D_) * D_);
    const f32x4* s4 = (const f32x4*)src;
    float s = 0.0f;
    #pragma unroll
    for (int j = 0; j < 8; ++j) {
        f32x4 v = __builtin_nontemporal_load(&s4[lane + j * 64]);
        s += (v.x + v.y) + (v.z + v.w);
    }
    s = wave_reduce_sum(s);
    if (lane == 0) {
        if (row < E_ * D_) Wsum[row] = s;
        else               bsum[row - E_ * D_] = s;
    }
}

__global__ __launch_bounds__(256) void token_kernel(
        const float* __restrict__ x, const float* __restrict__ wg,
        const float* __restrict__ Wsum, const float* __restrict__ bsum,
        float* __restrict__ y) {
    __shared__ float lw0[D_], lw1[D_], lg0[D_], lg1[D_];
    const int tid = threadIdx.x;
    {
        const f32x4* w0g = (const f32x4*)(Wsum);
        const f32x4* w1g = (const f32x4*)(Wsum + D_);
        const f32x4* wgg = (const f32x4*)(wg);
        f32x4* l0 = (f32x4*)lw0; f32x4* l1 = (f32x4*)lw1;
        f32x4* g0 = (f32x4*)lg0; f32x4* g1 = (f32x4*)lg1;
        for (int i = tid; i < D_ / 4; i += 256) {
            l0[i] = w0g[i]; l1[i] = w1g[i];
            f32x4 u = wgg[2 * i], v = wgg[2 * i + 1];
            f32x4 a, b;
            a.x = u.x; a.y = u.z; a.z = v.x; a.w = v.z;
            b.x = u.y; b.y = u.w; b.z = v.y; b.w = v.w;
            g0[i] = a; g1[i] = b;
        }
    }
    __syncthreads();
    const int wave = tid >> 6, lane = tid & 63;
    const int t0 = blockIdx.x * 8 + wave * 2, t1 = t0 + 1;
    const f32x4* xa = (const f32x4*)(x + (size_t)t0 * D_);
    const f32x4* xb = (const f32x4*)(x + (size_t)t1 * D_);
    const f32x4* l0 = (const f32x4*)lw0;
    const f32x4* l1 = (const f32x4*)lw1;
    const f32x4* c0 = (const f32x4*)lg0;
    const f32x4* c1 = (const f32x4*)lg1;
    float d0a = 0, d1a = 0, g0a = 0, g1a = 0;
    float d0b = 0, d1b = 0, g0b = 0, g1b = 0;
    #pragma unroll
    for (int j = 0; j < 8; ++j) {
        const int i = lane + j * 64;
        f32x4 x0 = __builtin_nontemporal_load(&xa[i]);
        f32x4 x1 = __builtin_nontemporal_load(&xb[i]);
        f32x4 a = l0[i], c = l1[i], u = c0[i], v = c1[i];
        d0a += x0.x * a.x + x0.y * a.y + x0.z * a.z + x0.w * a.w;
        d1a += x0.x * c.x + x0.y * c.y + x0.z * c.z + x0.w * c.w;
        g0a += x0.x * u.x + x0.y * u.y + x0.z * u.z + x0.w * u.w;
        g1a += x0.x * v.x + x0.y * v.y + x0.z * v.z + x0.w * v.w;
        d0b += x1.x * a.x + x1.y * a.y + x1.z * a.z + x1.w * a.w;
        d1b += x1.x * c.x + x1.y * c.y + x1.z * c.z + x1.w * c.w;
        g0b += x1.x * u.x + x1.y * u.y + x1.z * u.z + x1.w * u.w;
        g1b += x1.x * v.x + x1.y * v.y + x1.z * v.z + x1.w * v.w;
    }
    d0a = wave_reduce_sum(d0a); d1a = wave_reduce_sum(d1a);
    g0a = wave_reduce_sum(g0a); g1a = wave_reduce_sum(g1a);
    d0b = wave_reduce_sum(d0b); d1b = wave_reduce_sum(d1b);
    g0b = wave_reduce_sum(g0b); g1b = wave_reduce_sum(g1b);
    if (lane == 0) {
        {
            const int idx = (g1a > g0a) ? 1 : 0;
            const float diff = idx ? (g0a - g1a) : (g1a - g0a);
            const float gate = 1.0f / (1.0f + expf(diff));
            y[t0] = gate * ((idx ? d1a : d0a) + bsum[idx]);
        }
        {
            const int idx = (g1b > g0b) ? 1 : 0;
            const float diff = idx ? (g0b - g1b) : (g1b - g0b);
            const float gate = 1.0f / (1.0f + expf(diff));
            y[t1] = gate * ((idx ? d1b : d0b) + bsum[idx]);
        }
    }
}

__global__ __launch_bounds__(256) void logsoftmax_kernel(
        const float* __restrict__ y, float* __restrict__ out) {
    const int b = blockIdx.x;
    const f32x4* row4 = (const f32x4*)(y + (size_t)b * S_);
    f32x4 v = row4[threadIdx.x];
    float m = fmaxf(fmaxf(v.x, v.y), fmaxf(v.z, v.w));
    m = wave_reduce_max(m);
    __shared__ float lds[4];
    __shared__ float M_s, L_s;
    const int wave = threadIdx.x >> 6, lane = threadIdx.x & 63;
    if (lane == 0) lds[wave] = m;
    __syncthreads();
    if (threadIdx.x == 0) M_s = fmaxf(fmaxf(lds[0], lds[1]), fmaxf(lds[2], lds[3]));
    __syncthreads();
    const float M = M_s;
    float s = expf(v.x - M) + expf(v.y - M) + expf(v.z - M) + expf(v.w - M);
    s = wave_reduce_sum(s);
    __syncthreads();
    if (lane == 0) lds[wave] = s;
    __syncthreads();
    if (threadIdx.x == 0) L_s = M + logf(lds[0] + lds[1] + lds[2] + lds[3]);
    __syncthreads();
    const float lse = L_s;
    f32x4 o;
    o.x = v.x - lse; o.y = v.y - lse; o.z = v.z - lse; o.w = v.w - lse;
    ((f32x4*)(out + (size_t)b * S_))[threadIdx.x] = o;
}

extern "C" void kernel_launch(void* const* d_in, const int* in_sizes, int n_in,
                              void* d_out, int out_size, void* d_ws, size_t ws_size,
                              hipStream_t stream) {
    const float* x  = (const float*)d_in[0];
    const float* wg = (const float*)d_in[1];
    const float* W  = (const float*)d_in[2];
    const float* bv = (const float*)d_in[3];
    float* out = (float*)d_out;

    float* ws   = (float*)d_ws;
    float* Wsum = ws;
    float* bsum = ws + E_ * D_;
    float* y    = ws + E_ * D_ + 16;

    void* args[] = { (void*)&x, (void*)&wg, (void*)&W, (void*)&bv,
                     (void*)&Wsum, (void*)&bsum, (void*)&y, (void*)&out };
    hipError_t err = hipLaunchCooperativeKernel((const void*)fused_kernel,
                                                dim3(GRID_), dim3(256), args, 0, stream);
    if (err != hipSuccess) {
        (void)hipGetLastError();   // clear error, use proven 3-kernel path
        reduce_rows_kernel<<<(NROWS + 3) / 4, 256, 0, stream>>>(W, bv, Wsum, bsum);
        token_kernel<<<B_ * S_ / 8, 256, 0, stream>>>(x, wg, Wsum, bsum, y);
        logsoftmax_kernel<<<B_, 256, 0, stream>>>(y, out);
    }
}

// Round 7
// 423.324 us; speedup vs baseline: 1.0057x; 1.0057x over previous
//
#include <hip/hip_runtime.h>
#include <hip/hip_cooperative_groups.h>

namespace cg = cooperative_groups;

#define B_ 8
#define S_ 1024
#define D_ 2048
#define E_ 2
#define NROWS (E_ * D_ + E_)
#define GRID_ 1024   // 4 blocks/CU x 256 CUs: exact cooperative co-residency

typedef float f32x4 __attribute__((ext_vector_type(4)));

__device__ inline float wave_reduce_sum(float v) {
    #pragma unroll
    for (int off = 32; off > 0; off >>= 1) v += __shfl_down(v, off, 64);
    return v;
}
__device__ inline float wave_reduce_max(float v) {
    #pragma unroll
    for (int off = 32; off > 0; off >>= 1) v = fmaxf(v, __shfl_down(v, off, 64));
    return v;
}

// ==================== fused cooperative kernel ====================
// Phase A: W-row reduce (nt) + wg->LDS + x first-half prefetch into regs + gate partials
// Phase B: Wsum->LDS, dots (1st half from regs, 2nd half streamed), y write
// Phase C: log_softmax on blocks 0..7
__global__ __launch_bounds__(256, 4) void fused_kernel(
        const float* __restrict__ x, const float* __restrict__ wg,
        const float* __restrict__ W, const float* __restrict__ bvec,
        float* __restrict__ Wsum, float* __restrict__ bsum,
        float* __restrict__ y, float* __restrict__ out) {
    __shared__ float lw0[D_], lw1[D_], lg0[D_], lg1[D_];   // 32 KB
    __shared__ float red[4];
    __shared__ float M_s, L_s;
    const int tid = threadIdx.x;
    const int wave = tid >> 6, lane = tid & 63;
    cg::grid_group grid = cg::this_grid();

    // ---------------- Phase A ----------------
    // stage de-interleaved gate columns (wg is [D,2])
    {
        const f32x4* wgg = (const f32x4*)wg;
        f32x4* g0 = (f32x4*)lg0; f32x4* g1 = (f32x4*)lg1;
        for (int i = tid; i < D_ / 4; i += 256) {
            f32x4 u = wgg[2 * i], v = wgg[2 * i + 1];
            f32x4 a, b;
            a.x = u.x; a.y = u.z; a.z = v.x; a.w = v.z;
            b.x = u.y; b.y = u.w; b.z = v.y; b.w = v.w;
            g0[i] = a; g1[i] = b;
        }
    }

    // W row reduction: one row per wave (4096 rows over 1024 blocks)
    {
        const int row = blockIdx.x * 4 + wave;
        const f32x4* s4 = (const f32x4*)(W + (size_t)row * D_);
        float s = 0.0f;
        #pragma unroll
        for (int j = 0; j < 8; ++j) {
            f32x4 v = __builtin_nontemporal_load(&s4[lane + j * 64]);
            s += (v.x + v.y) + (v.z + v.w);
        }
        s = wave_reduce_sum(s);
        if (lane == 0) Wsum[row] = s;
        if (blockIdx.x == 0 && wave < E_) {            // bias rows
            const f32x4* b4 = (const f32x4*)(bvec + (size_t)wave * D_);
            float t = 0.0f;
            #pragma unroll
            for (int j = 0; j < 8; ++j) {
                f32x4 v = b4[lane + j * 64];
                t += (v.x + v.y) + (v.z + v.w);
            }
            t = wave_reduce_sum(t);
            if (lane == 0) bsum[wave] = t;
        }
    }
    __syncthreads();   // lg staged

    // x first-half prefetch (regs) + gate first-half partials
    const int t0 = blockIdx.x * 8 + wave * 2;
    const int t1 = t0 + 1;
    const f32x4* xa = (const f32x4*)(x + (size_t)t0 * D_);
    const f32x4* xb = (const f32x4*)(x + (size_t)t1 * D_);
    const f32x4* g0r = (const f32x4*)lg0;
    const f32x4* g1r = (const f32x4*)lg1;

    f32x4 xr0[4], xr1[4];
    #pragma unroll
    for (int j = 0; j < 4; ++j) {
        const int i = lane + j * 64;
        xr0[j] = __builtin_nontemporal_load(&xa[i]);
        xr1[j] = __builtin_nontemporal_load(&xb[i]);
    }
    float g0a = 0, g1a = 0, g0b = 0, g1b = 0;
    #pragma unroll
    for (int j = 0; j < 4; ++j) {
        const int i = lane + j * 64;
        f32x4 u = g0r[i], v = g1r[i];
        g0a += xr0[j].x * u.x + xr0[j].y * u.y + xr0[j].z * u.z + xr0[j].w * u.w;
        g1a += xr0[j].x * v.x + xr0[j].y * v.y + xr0[j].z * v.z + xr0[j].w * v.w;
        g0b += xr1[j].x * u.x + xr1[j].y * u.y + xr1[j].z * u.z + xr1[j].w * u.w;
        g1b += xr1[j].x * v.x + xr1[j].y * v.y + xr1[j].z * v.z + xr1[j].w * v.w;
    }

    __threadfence();
    grid.sync();

    // ---------------- Phase B ----------------
    {
        const f32x4* w0g = (const f32x4*)(Wsum);
        const f32x4* w1g = (const f32x4*)(Wsum + D_);
        f32x4* l0 = (f32x4*)lw0; f32x4* l1 = (f32x4*)lw1;
        for (int i = tid; i < D_ / 4; i += 256) { l0[i] = w0g[i]; l1[i] = w1g[i]; }
    }
    __syncthreads();

    const f32x4* l0r = (const f32x4*)lw0;
    const f32x4* l1r = (const f32x4*)lw1;
    float d0a = 0, d1a = 0, d0b = 0, d1b = 0;
    #pragma unroll
    for (int j = 0; j < 4; ++j) {            // first half: x from regs
        const int i = lane + j * 64;
        f32x4 a = l0r[i], c = l1r[i];
        d0a += xr0[j].x * a.x + xr0[j].y * a.y + xr0[j].z * a.z + xr0[j].w * a.w;
        d1a += xr0[j].x * c.x + xr0[j].y * c.y + xr0[j].z * c.z + xr0[j].w * c.w;
        d0b += xr1[j].x * a.x + xr1[j].y * a.y + xr1[j].z * a.z + xr1[j].w * a.w;
        d1b += xr1[j].x * c.x + xr1[j].y * c.y + xr1[j].z * c.z + xr1[j].w * c.w;
    }
    #pragma unroll
    for (int j = 4; j < 8; ++j) {            // second half: streamed
        const int i = lane + j * 64;
        f32x4 x0 = __builtin_nontemporal_load(&xa[i]);
        f32x4 x1 = __builtin_nontemporal_load(&xb[i]);
        f32x4 a = l0r[i], c = l1r[i], u = g0r[i], v = g1r[i];
        d0a += x0.x * a.x + x0.y * a.y + x0.z * a.z + x0.w * a.w;
        d1a += x0.x * c.x + x0.y * c.y + x0.z * c.z + x0.w * c.w;
        g0a += x0.x * u.x + x0.y * u.y + x0.z * u.z + x0.w * u.w;
        g1a += x0.x * v.x + x0.y * v.y + x0.z * v.z + x0.w * v.w;
        d0b += x1.x * a.x + x1.y * a.y + x1.z * a.z + x1.w * a.w;
        d1b += x1.x * c.x + x1.y * c.y + x1.z * c.z + x1.w * c.w;
        g0b += x1.x * u.x + x1.y * u.y + x1.z * u.z + x1.w * u.w;
        g1b += x1.x * v.x + x1.y * v.y + x1.z * v.z + x1.w * v.w;
    }
    d0a = wave_reduce_sum(d0a); d1a = wave_reduce_sum(d1a);
    g0a = wave_reduce_sum(g0a); g1a = wave_reduce_sum(g1a);
    d0b = wave_reduce_sum(d0b); d1b = wave_reduce_sum(d1b);
    g0b = wave_reduce_sum(g0b); g1b = wave_reduce_sum(g1b);

    if (lane == 0) {
        {
            const int idx = (g1a > g0a) ? 1 : 0;                 // argmax first-occurrence
            const float diff = idx ? (g0a - g1a) : (g1a - g0a);  // <= 0
            const float gate = 1.0f / (1.0f + expf(diff));
            y[t0] = gate * ((idx ? d1a : d0a) + bsum[idx]);
        }
        {
            const int idx = (g1b > g0b) ? 1 : 0;
            const float diff = idx ? (g0b - g1b) : (g1b - g0b);
            const float gate = 1.0f / (1.0f + expf(diff));
            y[t1] = gate * ((idx ? d1b : d0b) + bsum[idx]);
        }
    }

    __threadfence();
    grid.sync();

    // ---------------- Phase C: log_softmax (blocks 0..7) ----------------
    if (blockIdx.x < B_) {
        const int b = blockIdx.x;
        const f32x4* row4 = (const f32x4*)(y + (size_t)b * S_);
        f32x4 v = row4[tid];
        float m = fmaxf(fmaxf(v.x, v.y), fmaxf(v.z, v.w));
        m = wave_reduce_max(m);
        if (lane == 0) red[wave] = m;
        __syncthreads();
        if (tid == 0) M_s = fmaxf(fmaxf(red[0], red[1]), fmaxf(red[2], red[3]));
        __syncthreads();
        const float M = M_s;
        float s = expf(v.x - M) + expf(v.y - M) + expf(v.z - M) + expf(v.w - M);
        s = wave_reduce_sum(s);
        __syncthreads();
        if (lane == 0) red[wave] = s;
        __syncthreads();
        if (tid == 0) L_s = M + logf(red[0] + red[1] + red[2] + red[3]);
        __syncthreads();
        const float lse = L_s;
        f32x4 o;
        o.x = v.x - lse; o.y = v.y - lse; o.z = v.z - lse; o.w = v.w - lse;
        ((f32x4*)(out + (size_t)b * S_))[tid] = o;
    }
}

// ==================== fallback path (proven 3-kernel, nt loads) ====================
__global__ __launch_bounds__(256) void reduce_rows_kernel(
        const float* __restrict__ W, const float* __restrict__ bvec,
        float* __restrict__ Wsum, float* __restrict__ bsum) {
    const int wave = threadIdx.x >> 6, lane = threadIdx.x & 63;
    const int row = blockIdx.x * 4 + wave;
    if (row >= NROWS) return;
    const float* src = (row < E_ * D_) ? (W + (size_t)row * D_)
                                       : (bvec + (size_t)(row - E_ * D_) * D_);
    const f32x4* s4 = (const f32x4*)src;
    float s = 0.0f;
    #pragma unroll
    for (int j = 0; j < 8; ++j) {
        f32x4 v = __builtin_nontemporal_load(&s4[lane + j * 64]);
        s += (v.x + v.y) + (v.z + v.w);
    }
    s = wave_reduce_sum(s);
    if (lane == 0) {
        if (row < E_ * D_) Wsum[row] = s;
        else               bsum[row - E_ * D_] = s;
    }
}

__global__ __launch_bounds__(256) void token_kernel(
        const float* __restrict__ x, const float* __restrict__ wg,
        const float* __restrict__ Wsum, const float* __restrict__ bsum,
        float* __restrict__ y) {
    __shared__ float lw0[D_], lw1[D_], lg0[D_], lg1[D_];
    const int tid = threadIdx.x;
    {
        const f32x4* w0g = (const f32x4*)(Wsum);
        const f32x4* w1g = (const f32x4*)(Wsum + D_);
        const f32x4* wgg = (const f32x4*)(wg);
        f32x4* l0 = (f32x4*)lw0; f32x4* l1 = (f32x4*)lw1;
        f32x4* g0 = (f32x4*)lg0; f32x4* g1 = (f32x4*)lg1;
        for (int i = tid; i < D_ / 4; i += 256) {
            l0[i] = w0g[i]; l1[i] = w1g[i];
            f32x4 u = wgg[2 * i], v = wgg[2 * i + 1];
            f32x4 a, b;
            a.x = u.x; a.y = u.z; a.z = v.x; a.w = v.z;
            b.x = u.y; b.y = u.w; b.z = v.y; b.w = v.w;
            g0[i] = a; g1[i] = b;
        }
    }
    __syncthreads();
    const int wave = tid >> 6, lane = tid & 63;
    const int t0 = blockIdx.x * 8 + wave * 2, t1 = t0 + 1;
    const f32x4* xa = (const f32x4*)(x + (size_t)t0 * D_);
    const f32x4* xb = (const f32x4*)(x + (size_t)t1 * D_);
    const f32x4* l0 = (const f32x4*)lw0;
    const f32x4* l1 = (const f32x4*)lw1;
    const f32x4* c0 = (const f32x4*)lg0;
    const f32x4* c1 = (const f32x4*)lg1;
    float d0a = 0, d1a = 0, g0a = 0, g1a = 0;
    float d0b = 0, d1b = 0, g0b = 0, g1b = 0;
    #pragma unroll
    for (int j = 0; j < 8; ++j) {
        const int i = lane + j * 64;
        f32x4 x0 = __builtin_nontemporal_load(&xa[i]);
        f32x4 x1 = __builtin_nontemporal_load(&xb[i]);
        f32x4 a = l0[i], c = l1[i], u = c0[i], v = c1[i];
        d0a += x0.x * a.x + x0.y * a.y + x0.z * a.z + x0.w * a.w;
        d1a += x0.x * c.x + x0.y * c.y + x0.z * c.z + x0.w * c.w;
        g0a += x0.x * u.x + x0.y * u.y + x0.z * u.z + x0.w * u.w;
        g1a += x0.x * v.x + x0.y * v.y + x0.z * v.z + x0.w * v.w;
        d0b += x1.x * a.x + x1.y * a.y + x1.z * a.z + x1.w * a.w;
        d1b += x1.x * c.x + x1.y * c.y + x1.z * c.z + x1.w * c.w;
        g0b += x1.x * u.x + x1.y * u.y + x1.z * u.z + x1.w * u.w;
        g1b += x1.x * v.x + x1.y * v.y + x1.z * v.z + x1.w * v.w;
    }
    d0a = wave_reduce_sum(d0a); d1a = wave_reduce_sum(d1a);
    g0a = wave_reduce_sum(g0a); g1a = wave_reduce_sum(g1a);
    d0b = wave_reduce_sum(d0b); d1b = wave_reduce_sum(d1b);
    g0b = wave_reduce_sum(g0b); g1b = wave_reduce_sum(g1b);
    if (lane == 0) {
        {
            const int idx = (g1a > g0a) ? 1 : 0;
            const float diff = idx ? (g0a - g1a) : (g1a - g0a);
            const float gate = 1.0f / (1.0f + expf(diff));
            y[t0] = gate * ((idx ? d1a : d0a) + bsum[idx]);
        }
        {
            const int idx = (g1b > g0b) ? 1 : 0;
            const float diff = idx ? (g0b - g1b) : (g1b - g0b);
            const float gate = 1.0f / (1.0f + expf(diff));
            y[t1] = gate * ((idx ? d1b : d0b) + bsum[idx]);
        }
    }
}

__global__ __launch_bounds__(256) void logsoftmax_kernel(
        const float* __restrict__ y, float* __restrict__ out) {
    const int b = blockIdx.x;
    const f32x4* row4 = (const f32x4*)(y + (size_t)b * S_);
    f32x4 v = row4[threadIdx.x];
    float m = fmaxf(fmaxf(v.x, v.y), fmaxf(v.z, v.w));
    m = wave_reduce_max(m);
    __shared__ float lds[4];
    __shared__ float M_s, L_s;
    const int wave = threadIdx.x >> 6, lane = threadIdx.x & 63;
    if (lane == 0) lds[wave] = m;
    __syncthreads();
    if (threadIdx.x == 0) M_s = fmaxf(fmaxf(lds[0], lds[1]), fmaxf(lds[2], lds[3]));
    __syncthreads();
    const float M = M_s;
    float s = expf(v.x - M) + expf(v.y - M) + expf(v.z - M) + expf(v.w - M);
    s = wave_reduce_sum(s);
    __syncthreads();
    if (lane == 0) lds[wave] = s;
    __syncthreads();
    if (threadIdx.x == 0) L_s = M + logf(lds[0] + lds[1] + lds[2] + lds[3]);
    __syncthreads();
    const float lse = L_s;
    f32x4 o;
    o.x = v.x - lse; o.y = v.y - lse; o.z = v.z - lse; o.w = v.w - lse;
    ((f32x4*)(out + (size_t)b * S_))[threadIdx.x] = o;
}

extern "C" void kernel_launch(void* const* d_in, const int* in_sizes, int n_in,
                              void* d_out, int out_size, void* d_ws, size_t ws_size,
                              hipStream_t stream) {
    const float* x  = (const float*)d_in[0];
    const float* wg = (const float*)d_in[1];
    const float* W  = (const float*)d_in[2];
    const float* bv = (const float*)d_in[3];
    float* out = (float*)d_out;

    float* ws   = (float*)d_ws;
    float* Wsum = ws;
    float* bsum = ws + E_ * D_;
    float* y    = ws + E_ * D_ + 16;

    void* args[] = { (void*)&x, (void*)&wg, (void*)&W, (void*)&bv,
                     (void*)&Wsum, (void*)&bsum, (void*)&y, (void*)&out };
    hipError_t err = hipLaunchCooperativeKernel((const void*)fused_kernel,
                                                dim3(GRID_), dim3(256), args, 0, stream);
    if (err != hipSuccess) {
        (void)hipGetLastError();   // clear error, use proven 3-kernel path
        reduce_rows_kernel<<<(NROWS + 3) / 4, 256, 0, stream>>>(W, bv, Wsum, bsum);
        token_kernel<<<B_ * S_ / 8, 256, 0, stream>>>(x, wg, Wsum, bsum, y);
        logsoftmax_kernel<<<B_, 256, 0, stream>>>(y, out);
    }
}

// Round 8
// 243.875 us; speedup vs baseline: 1.7457x; 1.7358x over previous
//
#include <hip/hip_runtime.h>

#define B_ 8
#define S_ 1024
#define D_ 2048
#define E_ 2
#define GRID_ 1024   // exactly 4 blocks/CU x 256 CUs (co-residency proven in R7)

typedef float f32x4 __attribute__((ext_vector_type(4)));

__device__ inline float wave_reduce_sum(float v) {
    #pragma unroll
    for (int off = 32; off > 0; off >>= 1) v += __shfl_down(v, off, 64);
    return v;
}
__device__ inline float wave_reduce_max(float v) {
    #pragma unroll
    for (int off = 32; off > 0; off >>= 1) v = fmaxf(v, __shfl_down(v, off, 64));
    return v;
}

// ==================== single fused kernel, hand-rolled producer wait ====================
__global__ __launch_bounds__(256, 4) void fused_kernel(
        const float* __restrict__ x, const float* __restrict__ wg,
        const float* __restrict__ W, const float* __restrict__ bvec,
        float* __restrict__ Wsum, float* __restrict__ bsum,
        float* __restrict__ y, float* __restrict__ out,
        unsigned int* __restrict__ wcounter, unsigned int* __restrict__ dcounter) {
    __shared__ float lw0[D_], lw1[D_], lg0[D_], lg1[D_];   // 32 KB
    __shared__ float red[4];
    __shared__ float M_s, L_s;
    __shared__ int last_flag;
    const int tid = threadIdx.x;
    const int wave = tid >> 6, lane = tid & 63;

    // ---- stage de-interleaved gate columns (wg is [D,2]) ----
    {
        const f32x4* wgg = (const f32x4*)wg;
        f32x4* g0 = (f32x4*)lg0; f32x4* g1 = (f32x4*)lg1;
        for (int i = tid; i < D_ / 4; i += 256) {
            f32x4 u = wgg[2 * i], v = wgg[2 * i + 1];
            f32x4 a, b;
            a.x = u.x; a.y = u.z; a.z = v.x; a.w = v.z;
            b.x = u.y; b.y = u.w; b.z = v.y; b.w = v.w;
            g0[i] = a; g1[i] = b;
        }
    }

    // ---- W-row reduce: one row per wave (rows 4b..4b+3) ----
    {
        const int row = blockIdx.x * 4 + wave;
        const f32x4* s4 = (const f32x4*)(W + (size_t)row * D_);
        float s = 0.0f;
        #pragma unroll
        for (int j = 0; j < 8; ++j) {
            f32x4 v = __builtin_nontemporal_load(&s4[lane + j * 64]);
            s += (v.x + v.y) + (v.z + v.w);
        }
        s = wave_reduce_sum(s);
        if (lane == 0) Wsum[row] = s;
        if (blockIdx.x == 0 && wave < E_) {            // bias rows
            const f32x4* b4 = (const f32x4*)(bvec + (size_t)wave * D_);
            float t = 0.0f;
            #pragma unroll
            for (int j = 0; j < 8; ++j) {
                f32x4 v = b4[lane + j * 64];
                t += (v.x + v.y) + (v.z + v.w);
            }
            t = wave_reduce_sum(t);
            if (lane == 0) bsum[wave] = t;
        }
    }
    __syncthreads();                                   // block's Wsum rows + wg staged
    if (tid == 0) {
        __threadfence();                               // publish Wsum/bsum (agent scope)
        __hip_atomic_fetch_add(wcounter, 1u, __ATOMIC_RELEASE, __HIP_MEMORY_SCOPE_AGENT);
    }

    // ---- x first-half prefetch (regs) + gate first-half partials ----
    const int t0 = blockIdx.x * 8 + wave * 2;
    const int t1 = t0 + 1;
    const f32x4* xa = (const f32x4*)(x + (size_t)t0 * D_);
    const f32x4* xb = (const f32x4*)(x + (size_t)t1 * D_);
    const f32x4* g0r = (const f32x4*)lg0;
    const f32x4* g1r = (const f32x4*)lg1;

    f32x4 xr0[4], xr1[4];
    #pragma unroll
    for (int j = 0; j < 4; ++j) {
        const int i = lane + j * 64;
        xr0[j] = __builtin_nontemporal_load(&xa[i]);
        xr1[j] = __builtin_nontemporal_load(&xb[i]);
    }
    float g0a = 0, g1a = 0, g0b = 0, g1b = 0;
    #pragma unroll
    for (int j = 0; j < 4; ++j) {
        const int i = lane + j * 64;
        f32x4 u = g0r[i], v = g1r[i];
        g0a += xr0[j].x * u.x + xr0[j].y * u.y + xr0[j].z * u.z + xr0[j].w * u.w;
        g1a += xr0[j].x * v.x + xr0[j].y * v.y + xr0[j].z * v.z + xr0[j].w * v.w;
        g0b += xr1[j].x * u.x + xr1[j].y * u.y + xr1[j].z * u.z + xr1[j].w * u.w;
        g1b += xr1[j].x * v.x + xr1[j].y * v.y + xr1[j].z * v.z + xr1[j].w * v.w;
    }

    // ---- wait: all 1024 blocks published their Wsum rows ----
    if (tid == 0) {
        while (__hip_atomic_load(wcounter, __ATOMIC_ACQUIRE, __HIP_MEMORY_SCOPE_AGENT) < GRID_)
            __builtin_amdgcn_s_sleep(1);
        __threadfence();                               // acquire: invalidate stale lines
    }
    __syncthreads();

    // ---- stage Wsum -> LDS ----
    {
        const f32x4* w0g = (const f32x4*)(Wsum);
        const f32x4* w1g = (const f32x4*)(Wsum + D_);
        f32x4* l0 = (f32x4*)lw0; f32x4* l1 = (f32x4*)lw1;
        for (int i = tid; i < D_ / 4; i += 256) { l0[i] = w0g[i]; l1[i] = w1g[i]; }
    }
    __syncthreads();

    // ---- dots: first half from regs, second half streamed (+ gate 2nd half) ----
    const f32x4* l0r = (const f32x4*)lw0;
    const f32x4* l1r = (const f32x4*)lw1;
    float d0a = 0, d1a = 0, d0b = 0, d1b = 0;
    #pragma unroll
    for (int j = 0; j < 4; ++j) {
        const int i = lane + j * 64;
        f32x4 a = l0r[i], c = l1r[i];
        d0a += xr0[j].x * a.x + xr0[j].y * a.y + xr0[j].z * a.z + xr0[j].w * a.w;
        d1a += xr0[j].x * c.x + xr0[j].y * c.y + xr0[j].z * c.z + xr0[j].w * c.w;
        d0b += xr1[j].x * a.x + xr1[j].y * a.y + xr1[j].z * a.z + xr1[j].w * a.w;
        d1b += xr1[j].x * c.x + xr1[j].y * c.y + xr1[j].z * c.z + xr1[j].w * c.w;
    }
    #pragma unroll
    for (int j = 4; j < 8; ++j) {
        const int i = lane + j * 64;
        f32x4 x0 = __builtin_nontemporal_load(&xa[i]);
        f32x4 x1 = __builtin_nontemporal_load(&xb[i]);
        f32x4 a = l0r[i], c = l1r[i], u = g0r[i], v = g1r[i];
        d0a += x0.x * a.x + x0.y * a.y + x0.z * a.z + x0.w * a.w;
        d1a += x0.x * c.x + x0.y * c.y + x0.z * c.z + x0.w * c.w;
        g0a += x0.x * u.x + x0.y * u.y + x0.z * u.z + x0.w * u.w;
        g1a += x0.x * v.x + x0.y * v.y + x0.z * v.z + x0.w * v.w;
        d0b += x1.x * a.x + x1.y * a.y + x1.z * a.z + x1.w * a.w;
        d1b += x1.x * c.x + x1.y * c.y + x1.z * c.z + x1.w * c.w;
        g0b += x1.x * u.x + x1.y * u.y + x1.z * u.z + x1.w * u.w;
        g1b += x1.x * v.x + x1.y * v.y + x1.z * v.z + x1.w * v.w;
    }
    d0a = wave_reduce_sum(d0a); d1a = wave_reduce_sum(d1a);
    g0a = wave_reduce_sum(g0a); g1a = wave_reduce_sum(g1a);
    d0b = wave_reduce_sum(d0b); d1b = wave_reduce_sum(d1b);
    g0b = wave_reduce_sum(g0b); g1b = wave_reduce_sum(g1b);

    if (lane == 0) {
        {
            const int idx = (g1a > g0a) ? 1 : 0;                 // argmax first-occurrence
            const float diff = idx ? (g0a - g1a) : (g1a - g0a);  // <= 0
            const float gate = 1.0f / (1.0f + expf(diff));
            y[t0] = gate * ((idx ? d1a : d0a) + bsum[idx]);
        }
        {
            const int idx = (g1b > g0b) ? 1 : 0;
            const float diff = idx ? (g0b - g1b) : (g1b - g0b);
            const float gate = 1.0f / (1.0f + expf(diff));
            y[t1] = gate * ((idx ? d1b : d0b) + bsum[idx]);
        }
    }

    // ---- last-finisher election: epilogue block does log_softmax ----
    __syncthreads();                                   // all 4 waves' y stores issued
    if (tid == 0) {
        __threadfence();                               // publish y
        unsigned int old = __hip_atomic_fetch_add(dcounter, 1u, __ATOMIC_ACQ_REL,
                                                  __HIP_MEMORY_SCOPE_AGENT);
        last_flag = (old == GRID_ - 1) ? 1 : 0;
    }
    __syncthreads();
    if (!last_flag) return;

    __threadfence();                                   // acquire side for y reads
    for (int b = 0; b < B_; ++b) {
        const f32x4* row4 = (const f32x4*)(y + (size_t)b * S_);
        f32x4 v = row4[tid];
        float m = fmaxf(fmaxf(v.x, v.y), fmaxf(v.z, v.w));
        m = wave_reduce_max(m);
        if (lane == 0) red[wave] = m;
        __syncthreads();
        if (tid == 0) M_s = fmaxf(fmaxf(red[0], red[1]), fmaxf(red[2], red[3]));
        __syncthreads();
        const float M = M_s;
        float s = expf(v.x - M) + expf(v.y - M) + expf(v.z - M) + expf(v.w - M);
        s = wave_reduce_sum(s);
        __syncthreads();
        if (lane == 0) red[wave] = s;
        __syncthreads();
        if (tid == 0) L_s = M + logf(red[0] + red[1] + red[2] + red[3]);
        __syncthreads();
        const float lse = L_s;
        f32x4 o;
        o.x = v.x - lse; o.y = v.y - lse; o.z = v.z - lse; o.w = v.w - lse;
        ((f32x4*)(out + (size_t)b * S_))[tid] = o;
        __syncthreads();
    }
}

extern "C" void kernel_launch(void* const* d_in, const int* in_sizes, int n_in,
                              void* d_out, int out_size, void* d_ws, size_t ws_size,
                              hipStream_t stream) {
    const float* x  = (const float*)d_in[0];   // [B,S,D]
    const float* wg = (const float*)d_in[1];   // [D,E]
    const float* W  = (const float*)d_in[2];   // [E,D,D]
    const float* bv = (const float*)d_in[3];   // [E,D]
    float* out = (float*)d_out;                // [B,S]

    float* ws   = (float*)d_ws;
    float* Wsum = ws;                          // 4096 floats
    float* bsum = ws + E_ * D_;                // 2 floats
    float* y    = ws + E_ * D_ + 16;           // 8192 floats
    unsigned int* counters = (unsigned int*)((char*)d_ws + 49280);  // 64B-aligned, past y
    unsigned int* wcounter = counters;
    unsigned int* dcounter = counters + 1;

    hipMemsetAsync(counters, 0, 2 * sizeof(unsigned int), stream);  // deterministic per replay
    fused_kernel<<<GRID_, 256, 0, stream>>>(x, wg, W, bv, Wsum, bsum, y, out,
                                            wcounter, dcounter);
}

// Round 9
// 201.842 us; speedup vs baseline: 2.1092x; 1.2083x over previous
//
#include <hip/hip_runtime.h>

#define B_ 8
#define S_ 1024
#define D_ 2048
#define E_ 2
#define GRID_ 1024   // exactly 4 blocks/CU x 256 CUs (co-residency proven in R7/R8)

typedef float f32x4 __attribute__((ext_vector_type(4)));

__device__ inline float wave_reduce_sum(float v) {
    #pragma unroll
    for (int off = 32; off > 0; off >>= 1) v += __shfl_down(v, off, 64);
    return v;
}
__device__ inline float wave_reduce_max(float v) {
    #pragma unroll
    for (int off = 32; off > 0; off >>= 1) v = fmaxf(v, __shfl_down(v, off, 64));
    return v;
}

// ==================== single fused kernel, relaxed-poll producer wait ====================
__global__ __launch_bounds__(256, 4) void fused_kernel(
        const float* __restrict__ x, const float* __restrict__ wg,
        const float* __restrict__ W, const float* __restrict__ bvec,
        float* __restrict__ Wsum, float* __restrict__ bsum,
        float* __restrict__ y, float* __restrict__ out,
        unsigned int* __restrict__ wcounter, unsigned int* __restrict__ dcounter) {
    __shared__ float lw0[D_], lw1[D_], lg0[D_], lg1[D_];   // 32 KB
    __shared__ float red[4];
    __shared__ float M_s, L_s;
    __shared__ int last_flag;
    const int tid = threadIdx.x;
    const int wave = tid >> 6, lane = tid & 63;

    // ---- stage de-interleaved gate columns (wg is [D,2]) ----
    {
        const f32x4* wgg = (const f32x4*)wg;
        f32x4* g0 = (f32x4*)lg0; f32x4* g1 = (f32x4*)lg1;
        for (int i = tid; i < D_ / 4; i += 256) {
            f32x4 u = wgg[2 * i], v = wgg[2 * i + 1];
            f32x4 a, b;
            a.x = u.x; a.y = u.z; a.z = v.x; a.w = v.z;
            b.x = u.y; b.y = u.w; b.z = v.y; b.w = v.w;
            g0[i] = a; g1[i] = b;
        }
    }

    // ---- W-row reduce: one row per wave (rows 4b..4b+3) ----
    {
        const int row = blockIdx.x * 4 + wave;
        const f32x4* s4 = (const f32x4*)(W + (size_t)row * D_);
        float s = 0.0f;
        #pragma unroll
        for (int j = 0; j < 8; ++j) {
            f32x4 v = __builtin_nontemporal_load(&s4[lane + j * 64]);
            s += (v.x + v.y) + (v.z + v.w);
        }
        s = wave_reduce_sum(s);
        if (lane == 0) Wsum[row] = s;
        if (blockIdx.x == 0 && wave < E_) {            // bias rows
            const f32x4* b4 = (const f32x4*)(bvec + (size_t)wave * D_);
            float t = 0.0f;
            #pragma unroll
            for (int j = 0; j < 8; ++j) {
                f32x4 v = b4[lane + j * 64];
                t += (v.x + v.y) + (v.z + v.w);
            }
            t = wave_reduce_sum(t);
            if (lane == 0) bsum[wave] = t;
        }
    }
    __syncthreads();                                   // block's Wsum rows + wg staged
    if (tid == 0) {
        __threadfence();                               // publish Wsum/bsum
        __hip_atomic_fetch_add(wcounter, 1u, __ATOMIC_RELEASE, __HIP_MEMORY_SCOPE_AGENT);
    }

    // ---- x first-half prefetch (regs) + gate first-half partials ----
    const int t0 = blockIdx.x * 8 + wave * 2;
    const int t1 = t0 + 1;
    const f32x4* xa = (const f32x4*)(x + (size_t)t0 * D_);
    const f32x4* xb = (const f32x4*)(x + (size_t)t1 * D_);
    const f32x4* g0r = (const f32x4*)lg0;
    const f32x4* g1r = (const f32x4*)lg1;

    f32x4 xr0[4], xr1[4];
    #pragma unroll
    for (int j = 0; j < 4; ++j) {
        const int i = lane + j * 64;
        xr0[j] = __builtin_nontemporal_load(&xa[i]);
        xr1[j] = __builtin_nontemporal_load(&xb[i]);
    }
    float g0a = 0, g1a = 0, g0b = 0, g1b = 0;
    #pragma unroll
    for (int j = 0; j < 4; ++j) {
        const int i = lane + j * 64;
        f32x4 u = g0r[i], v = g1r[i];
        g0a += xr0[j].x * u.x + xr0[j].y * u.y + xr0[j].z * u.z + xr0[j].w * u.w;
        g1a += xr0[j].x * v.x + xr0[j].y * v.y + xr0[j].z * v.z + xr0[j].w * v.w;
        g0b += xr1[j].x * u.x + xr1[j].y * u.y + xr1[j].z * u.z + xr1[j].w * u.w;
        g1b += xr1[j].x * v.x + xr1[j].y * v.y + xr1[j].z * v.z + xr1[j].w * v.w;
    }

    // ---- wait: RELAXED poll (no per-iteration cache invalidate), fence ONCE after ----
    if (tid == 0) {
        while (__hip_atomic_load(wcounter, __ATOMIC_RELAXED, __HIP_MEMORY_SCOPE_AGENT) < GRID_)
            __builtin_amdgcn_s_sleep(4);
        __builtin_amdgcn_fence(__ATOMIC_ACQUIRE, "agent");   // single invalidate
    }
    __syncthreads();

    // ---- stage Wsum -> LDS ----
    {
        const f32x4* w0g = (const f32x4*)(Wsum);
        const f32x4* w1g = (const f32x4*)(Wsum + D_);
        f32x4* l0 = (f32x4*)lw0; f32x4* l1 = (f32x4*)lw1;
        for (int i = tid; i < D_ / 4; i += 256) { l0[i] = w0g[i]; l1[i] = w1g[i]; }
    }
    __syncthreads();

    // ---- dots: first half from regs, second half streamed (+ gate 2nd half) ----
    const f32x4* l0r = (const f32x4*)lw0;
    const f32x4* l1r = (const f32x4*)lw1;
    float d0a = 0, d1a = 0, d0b = 0, d1b = 0;
    #pragma unroll
    for (int j = 0; j < 4; ++j) {
        const int i = lane + j * 64;
        f32x4 a = l0r[i], c = l1r[i];
        d0a += xr0[j].x * a.x + xr0[j].y * a.y + xr0[j].z * a.z + xr0[j].w * a.w;
        d1a += xr0[j].x * c.x + xr0[j].y * c.y + xr0[j].z * c.z + xr0[j].w * c.w;
        d0b += xr1[j].x * a.x + xr1[j].y * a.y + xr1[j].z * a.z + xr1[j].w * a.w;
        d1b += xr1[j].x * c.x + xr1[j].y * c.y + xr1[j].z * c.z + xr1[j].w * c.w;
    }
    #pragma unroll
    for (int j = 4; j < 8; ++j) {
        const int i = lane + j * 64;
        f32x4 x0 = __builtin_nontemporal_load(&xa[i]);
        f32x4 x1 = __builtin_nontemporal_load(&xb[i]);
        f32x4 a = l0r[i], c = l1r[i], u = g0r[i], v = g1r[i];
        d0a += x0.x * a.x + x0.y * a.y + x0.z * a.z + x0.w * a.w;
        d1a += x0.x * c.x + x0.y * c.y + x0.z * c.z + x0.w * c.w;
        g0a += x0.x * u.x + x0.y * u.y + x0.z * u.z + x0.w * u.w;
        g1a += x0.x * v.x + x0.y * v.y + x0.z * v.z + x0.w * v.w;
        d0b += x1.x * a.x + x1.y * a.y + x1.z * a.z + x1.w * a.w;
        d1b += x1.x * c.x + x1.y * c.y + x1.z * c.z + x1.w * c.w;
        g0b += x1.x * u.x + x1.y * u.y + x1.z * u.z + x1.w * u.w;
        g1b += x1.x * v.x + x1.y * v.y + x1.z * v.z + x1.w * v.w;
    }
    d0a = wave_reduce_sum(d0a); d1a = wave_reduce_sum(d1a);
    g0a = wave_reduce_sum(g0a); g1a = wave_reduce_sum(g1a);
    d0b = wave_reduce_sum(d0b); d1b = wave_reduce_sum(d1b);
    g0b = wave_reduce_sum(g0b); g1b = wave_reduce_sum(g1b);

    if (lane == 0) {
        {
            const int idx = (g1a > g0a) ? 1 : 0;                 // argmax first-occurrence
            const float diff = idx ? (g0a - g1a) : (g1a - g0a);  // <= 0
            const float gate = 1.0f / (1.0f + expf(diff));
            y[t0] = gate * ((idx ? d1a : d0a) + bsum[idx]);
        }
        {
            const int idx = (g1b > g0b) ? 1 : 0;
            const float diff = idx ? (g0b - g1b) : (g1b - g0b);
            const float gate = 1.0f / (1.0f + expf(diff));
            y[t1] = gate * ((idx ? d1b : d0b) + bsum[idx]);
        }
    }

    // ---- last-finisher election: epilogue block does log_softmax ----
    __syncthreads();                                   // all 4 waves' y stores issued
    if (tid == 0) {
        __threadfence();                               // publish y
        unsigned int old = __hip_atomic_fetch_add(dcounter, 1u, __ATOMIC_ACQ_REL,
                                                  __HIP_MEMORY_SCOPE_AGENT);
        last_flag = (old == GRID_ - 1) ? 1 : 0;
    }
    __syncthreads();
    if (!last_flag) return;

    if (tid == 0) __builtin_amdgcn_fence(__ATOMIC_ACQUIRE, "agent");  // see others' y
    __syncthreads();
    for (int b = 0; b < B_; ++b) {
        const f32x4* row4 = (const f32x4*)(y + (size_t)b * S_);
        f32x4 v = row4[tid];
        float m = fmaxf(fmaxf(v.x, v.y), fmaxf(v.z, v.w));
        m = wave_reduce_max(m);
        if (lane == 0) red[wave] = m;
        __syncthreads();
        if (tid == 0) M_s = fmaxf(fmaxf(red[0], red[1]), fmaxf(red[2], red[3]));
        __syncthreads();
        const float M = M_s;
        float s = expf(v.x - M) + expf(v.y - M) + expf(v.z - M) + expf(v.w - M);
        s = wave_reduce_sum(s);
        __syncthreads();
        if (lane == 0) red[wave] = s;
        __syncthreads();
        if (tid == 0) L_s = M + logf(red[0] + red[1] + red[2] + red[3]);
        __syncthreads();
        const float lse = L_s;
        f32x4 o;
        o.x = v.x - lse; o.y = v.y - lse; o.z = v.z - lse; o.w = v.w - lse;
        ((f32x4*)(out + (size_t)b * S_))[tid] = o;
        __syncthreads();
    }
}

extern "C" void kernel_launch(void* const* d_in, const int* in_sizes, int n_in,
                              void* d_out, int out_size, void* d_ws, size_t ws_size,
                              hipStream_t stream) {
    const float* x  = (const float*)d_in[0];   // [B,S,D]
    const float* wg = (const float*)d_in[1];   // [D,E]
    const float* W  = (const float*)d_in[2];   // [E,D,D]
    const float* bv = (const float*)d_in[3];   // [E,D]
    float* out = (float*)d_out;                // [B,S]

    float* ws   = (float*)d_ws;
    float* Wsum = ws;                          // 4096 floats
    float* bsum = ws + E_ * D_;                // 2 floats
    float* y    = ws + E_ * D_ + 16;           // 8192 floats
    unsigned int* counters = (unsigned int*)((char*)d_ws + 49280);  // 64B-aligned, past y
    unsigned int* wcounter = counters;
    unsigned int* dcounter = counters + 1;

    hipMemsetAsync(counters, 0, 2 * sizeof(unsigned int), stream);  // deterministic per replay
    fused_kernel<<<GRID_, 256, 0, stream>>>(x, wg, W, bv, Wsum, bsum, y, out,
                                            wcounter, dcounter);
}

// Round 10
// 25.925 us; speedup vs baseline: 16.4220x; 7.7857x over previous
//
#include <hip/hip_runtime.h>

#define B_ 8
#define S_ 1024
#define D_ 2048
#define E_ 2
#define NROWS (E_ * D_ + E_)   // 4098 reduction rows (W rows + bias rows)

typedef float f32x4 __attribute__((ext_vector_type(4)));

__device__ inline float wave_reduce_sum(float v) {
    #pragma unroll
    for (int off = 32; off > 0; off >>= 1) v += __shfl_down(v, off, 64);
    return v;
}
__device__ inline float wave_reduce_max(float v) {
    #pragma unroll
    for (int off = 32; off > 0; off >>= 1) v = fmaxf(v, __shfl_down(v, off, 64));
    return v;
}

// ---------- kernel 1: Wsum[e,d] = sum_h W[e,d,h]; bsum[e] = sum_h b[e,h] ----------
// One WAVE per row (D=2048 floats = 8 f32x4/lane). 4 waves/block, no barriers.
__global__ __launch_bounds__(256) void reduce_rows_kernel(
        const float* __restrict__ W, const float* __restrict__ bvec,
        float* __restrict__ Wsum, float* __restrict__ bsum) {
    const int wave = threadIdx.x >> 6, lane = threadIdx.x & 63;
    const int row = blockIdx.x * 4 + wave;
    if (row >= NROWS) return;
    const float* src = (row < E_ * D_) ? (W + (size_t)row * D_)
                                       : (bvec + (size_t)(row - E_ * D_) * D_);
    const f32x4* s4 = (const f32x4*)src;
    float s = 0.0f;
    #pragma unroll
    for (int j = 0; j < 8; ++j) {
        f32x4 v = __builtin_nontemporal_load(&s4[lane + j * 64]);  // W streamed once
        s += (v.x + v.y) + (v.z + v.w);
    }
    s = wave_reduce_sum(s);
    if (lane == 0) {
        if (row < E_ * D_) Wsum[row] = s;
        else               bsum[row - E_ * D_] = s;
    }
}

// ---------- kernel 2: per-token gate + selected-expert row-sum ----------
// x first-half prefetched into regs BEFORE LDS staging (loads in flight across
// the stage + barrier). Weights staged in LDS once per block; 2 tokens/wave.
__global__ __launch_bounds__(256, 4) void token_kernel(
        const float* __restrict__ x, const float* __restrict__ wg,
        const float* __restrict__ Wsum, const float* __restrict__ bsum,
        float* __restrict__ y) {
    __shared__ float lw0[D_], lw1[D_], lg0[D_], lg1[D_];   // 32 KB -> 4 blocks/CU
    const int tid = threadIdx.x;
    const int wave = tid >> 6, lane = tid & 63;
    const int t0 = blockIdx.x * 8 + wave * 2;              // 2 tokens per wave
    const int t1 = t0 + 1;
    const f32x4* xa = (const f32x4*)(x + (size_t)t0 * D_);
    const f32x4* xb = (const f32x4*)(x + (size_t)t1 * D_);

    // ---- issue x first-half prefetch FIRST (independent of LDS) ----
    f32x4 xr0[4], xr1[4];
    #pragma unroll
    for (int j = 0; j < 4; ++j) {
        const int i = lane + j * 64;
        xr0[j] = __builtin_nontemporal_load(&xa[i]);
        xr1[j] = __builtin_nontemporal_load(&xb[i]);
    }

    // ---- stage: Wsum rows + de-interleaved wg columns (overlaps x loads) ----
    {
        const f32x4* w0g = (const f32x4*)(Wsum);
        const f32x4* w1g = (const f32x4*)(Wsum + D_);
        const f32x4* wgg = (const f32x4*)(wg);             // [D,2] interleaved
        f32x4* l0 = (f32x4*)lw0; f32x4* l1 = (f32x4*)lw1;
        f32x4* g0 = (f32x4*)lg0; f32x4* g1 = (f32x4*)lg1;
        #pragma unroll
        for (int i = tid; i < D_ / 4; i += 256) {
            l0[i] = w0g[i];
            l1[i] = w1g[i];
            f32x4 u = wgg[2 * i];
            f32x4 v = wgg[2 * i + 1];
            f32x4 a, b;
            a.x = u.x; a.y = u.z; a.z = v.x; a.w = v.z;    // expert-0 gate col
            b.x = u.y; b.y = u.w; b.z = v.y; b.w = v.w;    // expert-1 gate col
            g0[i] = a;
            g1[i] = b;
        }
    }
    __syncthreads();

    const f32x4* l0r = (const f32x4*)lw0;
    const f32x4* l1r = (const f32x4*)lw1;
    const f32x4* c0r = (const f32x4*)lg0;
    const f32x4* c1r = (const f32x4*)lg1;

    float d0a = 0, d1a = 0, g0a = 0, g1a = 0;
    float d0b = 0, d1b = 0, g0b = 0, g1b = 0;
    // ---- first half: x from registers ----
    #pragma unroll
    for (int j = 0; j < 4; ++j) {
        const int i = lane + j * 64;
        f32x4 a = l0r[i], c = l1r[i], u = c0r[i], v = c1r[i];
        d0a += xr0[j].x * a.x + xr0[j].y * a.y + xr0[j].z * a.z + xr0[j].w * a.w;
        d1a += xr0[j].x * c.x + xr0[j].y * c.y + xr0[j].z * c.z + xr0[j].w * c.w;
        g0a += xr0[j].x * u.x + xr0[j].y * u.y + xr0[j].z * u.z + xr0[j].w * u.w;
        g1a += xr0[j].x * v.x + xr0[j].y * v.y + xr0[j].z * v.z + xr0[j].w * v.w;
        d0b += xr1[j].x * a.x + xr1[j].y * a.y + xr1[j].z * a.z + xr1[j].w * a.w;
        d1b += xr1[j].x * c.x + xr1[j].y * c.y + xr1[j].z * c.z + xr1[j].w * c.w;
        g0b += xr1[j].x * u.x + xr1[j].y * u.y + xr1[j].z * u.z + xr1[j].w * u.w;
        g1b += xr1[j].x * v.x + xr1[j].y * v.y + xr1[j].z * v.z + xr1[j].w * v.w;
    }
    // ---- second half: x streamed ----
    #pragma unroll
    for (int j = 4; j < 8; ++j) {
        const int i = lane + j * 64;
        f32x4 x0 = __builtin_nontemporal_load(&xa[i]);
        f32x4 x1 = __builtin_nontemporal_load(&xb[i]);
        f32x4 a = l0r[i], c = l1r[i], u = c0r[i], v = c1r[i];
        d0a += x0.x * a.x + x0.y * a.y + x0.z * a.z + x0.w * a.w;
        d1a += x0.x * c.x + x0.y * c.y + x0.z * c.z + x0.w * c.w;
        g0a += x0.x * u.x + x0.y * u.y + x0.z * u.z + x0.w * u.w;
        g1a += x0.x * v.x + x0.y * v.y + x0.z * v.z + x0.w * v.w;
        d0b += x1.x * a.x + x1.y * a.y + x1.z * a.z + x1.w * a.w;
        d1b += x1.x * c.x + x1.y * c.y + x1.z * c.z + x1.w * c.w;
        g0b += x1.x * u.x + x1.y * u.y + x1.z * u.z + x1.w * u.w;
        g1b += x1.x * v.x + x1.y * v.y + x1.z * v.z + x1.w * v.w;
    }
    d0a = wave_reduce_sum(d0a); d1a = wave_reduce_sum(d1a);
    g0a = wave_reduce_sum(g0a); g1a = wave_reduce_sum(g1a);
    d0b = wave_reduce_sum(d0b); d1b = wave_reduce_sum(d1b);
    g0b = wave_reduce_sum(g0b); g1b = wave_reduce_sum(g1b);

    if (lane == 0) {
        // jnp.argmax: first occurrence of max -> idx=1 only on strict g1 > g0
        {
            const int idx = (g1a > g0a) ? 1 : 0;
            const float diff = idx ? (g0a - g1a) : (g1a - g0a);  // <= 0
            const float gate = 1.0f / (1.0f + expf(diff));
            y[t0] = gate * ((idx ? d1a : d0a) + bsum[idx]);
        }
        {
            const int idx = (g1b > g0b) ? 1 : 0;
            const float diff = idx ? (g0b - g1b) : (g1b - g0b);
            const float gate = 1.0f / (1.0f + expf(diff));
            y[t1] = gate * ((idx ? d1b : d0b) + bsum[idx]);
        }
    }
}

// ---------- kernel 3: log_softmax over axis=1 (S) ----------
// One block per batch row; row held in registers (256 threads x f32x4).
__global__ __launch_bounds__(256) void logsoftmax_kernel(
        const float* __restrict__ y, float* __restrict__ out) {
    const int b = blockIdx.x;
    const f32x4* row4 = (const f32x4*)(y + (size_t)b * S_);
    f32x4 v = row4[threadIdx.x];

    float m = fmaxf(fmaxf(v.x, v.y), fmaxf(v.z, v.w));
    m = wave_reduce_max(m);
    __shared__ float lds[4];
    __shared__ float M_s, L_s;
    const int wave = threadIdx.x >> 6, lane = threadIdx.x & 63;
    if (lane == 0) lds[wave] = m;
    __syncthreads();
    if (threadIdx.x == 0)
        M_s = fmaxf(fmaxf(lds[0], lds[1]), fmaxf(lds[2], lds[3]));
    __syncthreads();
    const float M = M_s;

    float s = expf(v.x - M) + expf(v.y - M) + expf(v.z - M) + expf(v.w - M);
    s = wave_reduce_sum(s);
    __syncthreads();
    if (lane == 0) lds[wave] = s;
    __syncthreads();
    if (threadIdx.x == 0)
        L_s = M + logf(lds[0] + lds[1] + lds[2] + lds[3]);
    __syncthreads();
    const float lse = L_s;

    f32x4 o;
    o.x = v.x - lse; o.y = v.y - lse; o.z = v.z - lse; o.w = v.w - lse;
    ((f32x4*)(out + (size_t)b * S_))[threadIdx.x] = o;
}

extern "C" void kernel_launch(void* const* d_in, const int* in_sizes, int n_in,
                              void* d_out, int out_size, void* d_ws, size_t ws_size,
                              hipStream_t stream) {
    const float* x  = (const float*)d_in[0];   // [B,S,D]
    const float* wg = (const float*)d_in[1];   // [D,E]
    const float* W  = (const float*)d_in[2];   // [E,D,D]
    const float* bv = (const float*)d_in[3];   // [E,D]
    float* out = (float*)d_out;                // [B,S]

    float* ws   = (float*)d_ws;
    float* Wsum = ws;                  // E*D = 4096 floats
    float* bsum = ws + E_ * D_;        // 2 floats
    float* y    = ws + E_ * D_ + 16;   // B*S = 8192 floats (16B-aligned offset)

    reduce_rows_kernel<<<(NROWS + 3) / 4, 256, 0, stream>>>(W, bv, Wsum, bsum);
    token_kernel<<<B_ * S_ / 8, 256, 0, stream>>>(x, wg, Wsum, bsum, y);
    logsoftmax_kernel<<<B_, 256, 0, stream>>>(y, out);
}